// Round 1
// baseline (1077.540 us; speedup 1.0000x reference)
//
#include <hip/hip_runtime.h>

// ============================================================================
// GLM4-MoE attention layer on MI355X (gfx950), fp16 MFMA pipeline.
// Stages: cvt(hidden) + transpose-cvt(weights) -> GEMM1(qkv, fused scatter)
//         -> RoPE(q,k) -> V transpose -> flash attention -> GEMM2 -> f32 out.
// Round 1: correctness-first. Known deferred perf items:
//   - LDS bank conflicts on fragment reads (8-way GEMM, 16-way attn) -> T2 swizzle
//   - single-buffered 2-barrier K-loop (m97 structure ~900 TF ceiling) -> 8-phase
// Declared risk: 16x16x32 A/B fragment layout assumed k = 8*(lane>>4)+e contiguous.
// ============================================================================

typedef _Float16 f16;
typedef _Float16 f16x8 __attribute__((ext_vector_type(8)));
typedef float f32x4 __attribute__((ext_vector_type(4)));

static constexpr int Bn = 2, Sn = 2048, Hn = 4096, NH = 32, NKV = 8, HD = 128;
static constexpr int Mn = Bn * Sn;               // 4096 tokens
static constexpr int NQKV = (NH + 2 * NKV) * HD; // 6144
static constexpr float SM_SCALE = 0.08838834764831845f; // 1/sqrt(128)

#define AS1 __attribute__((address_space(1)))
#define AS3 __attribute__((address_space(3)))

// async global->LDS, 16B per lane. lds arg must be wave-uniform (HW adds lane*16).
__device__ __forceinline__ void async_ld16(const void* g, void* l) {
    __builtin_amdgcn_global_load_lds((const AS1 void*)g, (AS3 void*)l, 16, 0, 0);
}

// ---------------------------------------------------------------------------
// f32 -> f16 elementwise, 8 elems/thread (n divisible by 8)
__global__ void k_cvt(const float* __restrict__ src, f16* __restrict__ dst, long n) {
    long i = ((long)blockIdx.x * blockDim.x + threadIdx.x) * 8;
    if (i >= n) return;
    float4 a = *(const float4*)(src + i);
    float4 b = *(const float4*)(src + i + 4);
    f16x8 o = {(f16)a.x, (f16)a.y, (f16)a.z, (f16)a.w,
               (f16)b.x, (f16)b.y, (f16)b.z, (f16)b.w};
    *(f16x8*)(dst + i) = o;
}

// ---------------------------------------------------------------------------
// transpose + convert: src f32 [K][N] -> dst f16 [N][K], dst row stride rs elems
__global__ void k_tcvt(const float* __restrict__ src, f16* __restrict__ dst,
                       int K, int N, long rs) {
    __shared__ float tile[32][33];
    int k0 = blockIdx.y * 32, n0 = blockIdx.x * 32;
    int tx = threadIdx.x, ty = threadIdx.y;
#pragma unroll
    for (int r = ty; r < 32; r += 8)
        tile[r][tx] = src[(long)(k0 + r) * N + (n0 + tx)];
    __syncthreads();
#pragma unroll
    for (int r = ty; r < 32; r += 8)
        dst[(long)(n0 + r) * rs + (k0 + tx)] = (f16)tile[tx][r];
}

// ---------------------------------------------------------------------------
// RoPE in-place, interleaved pairs on first 64 dims. x layout [b][nheads][s][128].
// pair i uses cos[b][s][i], sin[b][s][i] (i in [0,32)).
__global__ void k_rope(f16* __restrict__ x, const float* __restrict__ cosb,
                       const float* __restrict__ sinb, int nheads) {
    long idx = (long)blockIdx.x * blockDim.x + threadIdx.x;
    int i = (int)(idx & 31);
    long t = idx >> 5;                 // (b*nheads + h)*S + s
    int s = (int)(t & (Sn - 1));
    int bh = (int)(t >> 11);
    int b = bh / nheads;
    long base = t * HD + 2 * i;
    float c = cosb[((long)b * Sn + s) * 64 + i];
    float sv = sinb[((long)b * Sn + s) * 64 + i];
    float x0 = (float)x[base], x1 = (float)x[base + 1];
    x[base]     = (f16)(x0 * c - x1 * sv);
    x[base + 1] = (f16)(x1 * c + x0 * sv);
}

// ---------------------------------------------------------------------------
// V transpose per (b,kv): [S][HD] -> [HD][S]
__global__ void k_tv(const f16* __restrict__ v, f16* __restrict__ vt) {
    __shared__ f16 tile[32][33];
    int bk = blockIdx.z;
    int s0 = blockIdx.x * 32, d0 = blockIdx.y * 32;
    const f16* src = v + (long)bk * Sn * HD;
    f16* dst = vt + (long)bk * Sn * HD;
    int tx = threadIdx.x, ty = threadIdx.y;
#pragma unroll
    for (int r = ty; r < 32; r += 8)
        tile[r][tx] = src[(long)(s0 + r) * HD + (d0 + tx)];
    __syncthreads();
#pragma unroll
    for (int r = ty; r < 32; r += 8)
        dst[(long)(d0 + r) * Sn + (s0 + tx)] = tile[tx][r];
}

// ---------------------------------------------------------------------------
// GEMM core: A f16 [M][4096] row-major, Bt f16 [N][4096] row-major (B transposed).
// 128x128 tile, BK=32, 4 waves (2x2) x (4x4) 16x16x32 fragments. m97 structure.
__device__ __forceinline__ void gemm_core(const f16* __restrict__ A,
                                          const f16* __restrict__ Bt,
                                          f16* Asm, f16* Bsm,
                                          int m0, int n0, f32x4 acc[4][4]) {
    const int t = threadIdx.x, lane = t & 63, wave = t >> 6;
    const int wr = wave >> 1, wc = wave & 1;
    const int fr = lane & 15, fg = lane >> 4;
    const int srow = t >> 2;        // 0..63
    const int scol = (t & 3) * 8;
    const f16* ga = A + (long)(m0 + srow) * 4096 + scol;
    const f16* gb = Bt + (long)(n0 + srow) * 4096 + scol;

    for (int k0 = 0; k0 < 4096; k0 += 32) {
        __syncthreads(); // previous iter's fragment reads done before overwrite
        async_ld16(ga + k0,               Asm + wave * 512);
        async_ld16(ga + 64 * 4096 + k0,   Asm + 2048 + wave * 512);
        async_ld16(gb + k0,               Bsm + wave * 512);
        async_ld16(gb + 64 * 4096 + k0,   Bsm + 2048 + wave * 512);
        asm volatile("s_waitcnt vmcnt(0)" ::: "memory");
        __syncthreads();

        f16x8 af[4], bf[4];
#pragma unroll
        for (int mm = 0; mm < 4; ++mm)
            af[mm] = *(const f16x8*)&Asm[(wr * 64 + mm * 16 + fr) * 32 + 8 * fg];
#pragma unroll
        for (int nn = 0; nn < 4; ++nn)
            bf[nn] = *(const f16x8*)&Bsm[(wc * 64 + nn * 16 + fr) * 32 + 8 * fg];
#pragma unroll
        for (int mm = 0; mm < 4; ++mm)
#pragma unroll
            for (int nn = 0; nn < 4; ++nn)
                acc[mm][nn] = __builtin_amdgcn_mfma_f32_16x16x32_f16(
                    af[mm], bf[nn], acc[mm][nn], 0, 0, 0);
    }
}

// GEMM1: hidden[4096][4096] @ Wqkv^T[6144][4096] -> scatter q/k/v f16
__global__ __launch_bounds__(256) void k_gemm_qkv(
    const f16* __restrict__ A, const f16* __restrict__ Bt,
    f16* __restrict__ q, f16* __restrict__ kk_, f16* __restrict__ v) {
    __shared__ __align__(16) f16 Asm[128 * 32];
    __shared__ __align__(16) f16 Bsm[128 * 32];
    int n0 = blockIdx.x * 128, m0 = blockIdx.y * 128;
    f32x4 acc[4][4] = {};
    gemm_core(A, Bt, Asm, Bsm, m0, n0, acc);

    const int lane = threadIdx.x & 63, wave = threadIdx.x >> 6;
    const int wr = wave >> 1, wc = wave & 1;
    const int fr = lane & 15, fg = lane >> 4;
#pragma unroll
    for (int mm = 0; mm < 4; ++mm) {
        int r0 = m0 + wr * 64 + mm * 16 + 4 * fg;
#pragma unroll
        for (int nn = 0; nn < 4; ++nn) {
            int c = n0 + wc * 64 + nn * 16 + fr;
#pragma unroll
            for (int e = 0; e < 4; ++e) {
                int r = r0 + e;
                int b = r >> 11, s = r & (Sn - 1);
                f16 val = (f16)acc[mm][nn][e];
                int d = c & 127;
                if (c < 4096) {
                    int h = c >> 7;
                    q[(((long)b * NH + h) * Sn + s) * HD + d] = val;
                } else if (c < 5120) {
                    int h = (c - 4096) >> 7;
                    kk_[(((long)b * NKV + h) * Sn + s) * HD + d] = val;
                } else {
                    int h = (c - 5120) >> 7;
                    v[(((long)b * NKV + h) * Sn + s) * HD + d] = val;
                }
            }
        }
    }
}

// GEMM2: attn_out[4096][4096] @ wo^T[4096][4096] -> d_out f32
__global__ __launch_bounds__(256) void k_gemm_out(
    const f16* __restrict__ A, const f16* __restrict__ Bt,
    float* __restrict__ out) {
    __shared__ __align__(16) f16 Asm[128 * 32];
    __shared__ __align__(16) f16 Bsm[128 * 32];
    int n0 = blockIdx.x * 128, m0 = blockIdx.y * 128;
    f32x4 acc[4][4] = {};
    gemm_core(A, Bt, Asm, Bsm, m0, n0, acc);

    const int lane = threadIdx.x & 63, wave = threadIdx.x >> 6;
    const int wr = wave >> 1, wc = wave & 1;
    const int fr = lane & 15, fg = lane >> 4;
#pragma unroll
    for (int mm = 0; mm < 4; ++mm) {
        int r0 = m0 + wr * 64 + mm * 16 + 4 * fg;
#pragma unroll
        for (int nn = 0; nn < 4; ++nn) {
            int c = n0 + wc * 64 + nn * 16 + fr;
#pragma unroll
            for (int e = 0; e < 4; ++e)
                out[(long)(r0 + e) * 4096 + c] = acc[mm][nn][e];
        }
    }
}

// ---------------------------------------------------------------------------
// Flash attention, causal, GQA (4 q-heads per kv-head).
// grid (S/64, NH, B), 256 threads = 4 waves, each wave owns 16 q-rows.
// Q [b][h][s][d]; K [b][kv][s][d]; Vt [b][kv][d][s]; O [token][NH*HD].
__global__ __launch_bounds__(256) void k_attn(
    const f16* __restrict__ Q, const f16* __restrict__ K,
    const f16* __restrict__ Vt, f16* __restrict__ O) {
    __shared__ __align__(16) f16 Ksm[64 * 128];   // [kv s][hd]
    __shared__ __align__(16) f16 Vsm[128 * 64];   // [hd][kv s]
    __shared__ __align__(16) f16 Psm[4 * 16 * 72]; // per-wave [16 q][64 kv] pad->72

    const int q0 = blockIdx.x * 64;
    const int h = blockIdx.y, b = blockIdx.z;
    const int kvh = h >> 2;
    const int t = threadIdx.x, lane = t & 63, wave = t >> 6;
    const int q0w = q0 + wave * 16;
    const int fr = lane & 15, fg = lane >> 4;

    const f16* Qb = Q + ((long)(b * NH + h) * Sn) * HD;
    const f16* Kb = K + ((long)(b * NKV + kvh) * Sn) * HD;
    const f16* Vb = Vt + ((long)(b * NKV + kvh) * HD) * Sn;

    f16x8 qf[4];
#pragma unroll
    for (int kk = 0; kk < 4; ++kk)
        qf[kk] = *(const f16x8*)&Qb[(long)(q0w + fr) * HD + kk * 32 + 8 * fg];

    f32x4 oacc[8] = {};
    float mrun[4], lrun[4];
#pragma unroll
    for (int e = 0; e < 4; ++e) { mrun[e] = -1e30f; lrun[e] = 0.f; }

    const int ntiles = q0 / 64 + 1;
    for (int kt = 0; kt < ntiles; ++kt) {
        const int k0 = kt * 64;
        __syncthreads();
#pragma unroll
        for (int p = 0; p < 4; ++p) {
            { // K tile [64][128]: elem offset p*2048 + t*8
                int eo = p * 2048 + t * 8;
                int row = eo >> 7, col = eo & 127;
                async_ld16(Kb + (long)(k0 + row) * HD + col, Ksm + p * 2048 + wave * 512);
            }
            { // Vt tile [128][64]
                int eo = p * 2048 + t * 8;
                int row = eo >> 6, col = eo & 63;
                async_ld16(Vb + (long)row * Sn + k0 + col, Vsm + p * 2048 + wave * 512);
            }
        }
        asm volatile("s_waitcnt vmcnt(0)" ::: "memory");
        __syncthreads();

        if (k0 <= q0w + 15) {
            // ---- scores: Q(16x128) . K^T(128x64)
            f32x4 sacc[4] = {};
#pragma unroll
            for (int nn = 0; nn < 4; ++nn)
#pragma unroll
                for (int kk = 0; kk < 4; ++kk) {
                    f16x8 kf = *(const f16x8*)&Ksm[(nn * 16 + fr) * 128 + kk * 32 + 8 * fg];
                    sacc[nn] = __builtin_amdgcn_mfma_f32_16x16x32_f16(qf[kk], kf, sacc[nn], 0, 0, 0);
                }
            // ---- mask + scale + row max
            float rmax[4] = {-1e30f, -1e30f, -1e30f, -1e30f};
#pragma unroll
            for (int nn = 0; nn < 4; ++nn)
#pragma unroll
                for (int e = 0; e < 4; ++e) {
                    float sv = sacc[nn][e] * SM_SCALE;
                    int skv = k0 + nn * 16 + fr;
                    int sq = q0w + 4 * fg + e;
                    sv = (skv <= sq) ? sv : -1e30f;
                    sacc[nn][e] = sv;
                    rmax[e] = fmaxf(rmax[e], sv);
                }
#pragma unroll
            for (int e = 0; e < 4; ++e)
#pragma unroll
                for (int msk = 1; msk < 16; msk <<= 1)
                    rmax[e] = fmaxf(rmax[e], __shfl_xor(rmax[e], msk, 64));
            // ---- online softmax update
            float sc[4], rsum[4];
#pragma unroll
            for (int e = 0; e < 4; ++e) {
                float mn = fmaxf(mrun[e], rmax[e]);
                sc[e] = __expf(mrun[e] - mn);
                mrun[e] = mn;
                lrun[e] *= sc[e];
                rsum[e] = 0.f;
            }
#pragma unroll
            for (int nn = 0; nn < 4; ++nn)
#pragma unroll
                for (int e = 0; e < 4; ++e) {
                    float pv = __expf(sacc[nn][e] - mrun[e]); // masked -> exp(-1e30)=0
                    rsum[e] += pv;
                    Psm[wave * 1152 + (4 * fg + e) * 72 + nn * 16 + fr] = (f16)pv;
                }
#pragma unroll
            for (int e = 0; e < 4; ++e) {
#pragma unroll
                for (int msk = 1; msk < 16; msk <<= 1)
                    rsum[e] += __shfl_xor(rsum[e], msk, 64);
                lrun[e] += rsum[e];
            }
#pragma unroll
            for (int nd = 0; nd < 8; ++nd)
#pragma unroll
                for (int e = 0; e < 4; ++e)
                    oacc[nd][e] *= sc[e];
            // P writes -> P reads are same-wave LDS (in-order); fence for safety
            asm volatile("s_waitcnt lgkmcnt(0)" ::: "memory");
            // ---- PV: P(16x64) . V(64x128)
#pragma unroll
            for (int kk = 0; kk < 2; ++kk) {
                f16x8 pf = *(const f16x8*)&Psm[wave * 1152 + fr * 72 + kk * 32 + 8 * fg];
#pragma unroll
                for (int nd = 0; nd < 8; ++nd) {
                    f16x8 vf = *(const f16x8*)&Vsm[(nd * 16 + fr) * 64 + kk * 32 + 8 * fg];
                    oacc[nd] = __builtin_amdgcn_mfma_f32_16x16x32_f16(pf, vf, oacc[nd], 0, 0, 0);
                }
            }
        }
    }
    // ---- epilogue: normalize + store
    float inv[4];
#pragma unroll
    for (int e = 0; e < 4; ++e) inv[e] = 1.f / lrun[e];
#pragma unroll
    for (int nd = 0; nd < 8; ++nd)
#pragma unroll
        for (int e = 0; e < 4; ++e) {
            int srow = q0w + 4 * fg + e;
            long tok = (long)b * Sn + srow;
            O[tok * (NH * HD) + h * HD + nd * 16 + fr] = (f16)(oacc[nd][e] * inv[e]);
        }
}

// sentinel if workspace too small (distinctive absmax ~1e9)
__global__ void k_ws_fail(float* out) { out[0] = 1.0e9f; }

// ---------------------------------------------------------------------------
extern "C" void kernel_launch(void* const* d_in, const int* in_sizes, int n_in,
                              void* d_out, int out_size, void* d_ws, size_t ws_size,
                              hipStream_t stream) {
    const float* hs   = (const float*)d_in[0];
    const float* wq   = (const float*)d_in[1];
    const float* wk   = (const float*)d_in[2];
    const float* wv   = (const float*)d_in[3];
    const float* wo   = (const float*)d_in[4];
    const float* cosb = (const float*)d_in[5];
    const float* sinb = (const float*)d_in[6];
    float* out = (float*)d_out;

    // workspace layout (bytes)
    const size_t OFF_WQKV = 0;                         // [6144][4096] f16
    const size_t OFF_WO   = 50331648;                  // [4096][4096] f16
    const size_t OFF_HID  = 83886080;                  // [4096][4096] f16 (later attn_out)
    const size_t OFF_Q    = 117440512;                 // [2][32][2048][128] f16
    const size_t OFF_K    = 150994944;                 // [2][8][2048][128] f16
    const size_t OFF_V    = 159383552;                 // [2][8][2048][128] f16
    const size_t OFF_VT   = 167772160;                 // [2][8][128][2048] f16
    const size_t WS_NEED  = 176160768;
    if (ws_size < WS_NEED) { k_ws_fail<<<1, 1, 0, stream>>>(out); return; }

    char* ws = (char*)d_ws;
    f16* wqkv_t = (f16*)(ws + OFF_WQKV);
    f16* wo_t   = (f16*)(ws + OFF_WO);
    f16* hid    = (f16*)(ws + OFF_HID);
    f16* qb     = (f16*)(ws + OFF_Q);
    f16* kb     = (f16*)(ws + OFF_K);
    f16* vb     = (f16*)(ws + OFF_V);
    f16* vtb    = (f16*)(ws + OFF_VT);

    dim3 tb(32, 8);
    // convert hidden f32 -> f16
    k_cvt<<<dim3(16777216 / (256 * 8)), 256, 0, stream>>>(hs, hid, 16777216L);
    // weights -> f16 transposed [N][K]
    k_tcvt<<<dim3(128, 128), tb, 0, stream>>>(wq, wqkv_t, 4096, 4096, 4096);
    k_tcvt<<<dim3(32, 128),  tb, 0, stream>>>(wk, wqkv_t + (long)4096 * 4096, 4096, 1024, 4096);
    k_tcvt<<<dim3(32, 128),  tb, 0, stream>>>(wv, wqkv_t + (long)5120 * 4096, 4096, 1024, 4096);
    k_tcvt<<<dim3(128, 128), tb, 0, stream>>>(wo, wo_t, 4096, 4096, 4096);
    // QKV projection (scatters into q/k/v head layouts)
    k_gemm_qkv<<<dim3(48, 32), 256, 0, stream>>>(hid, wqkv_t, qb, kb, vb);
    // partial interleaved RoPE on q and k
    k_rope<<<dim3(2 * 32 * 2048 * 32 / 256), 256, 0, stream>>>(qb, cosb, sinb, NH);
    k_rope<<<dim3(2 * 8 * 2048 * 32 / 256), 256, 0, stream>>>(kb, cosb, sinb, NKV);
    // V -> V^T (d-major) for PV fragment reads
    k_tv<<<dim3(64, 4, 16), tb, 0, stream>>>(vb, vtb);
    // flash attention (writes attn_out into hid buffer — hid no longer needed)
    k_attn<<<dim3(32, 32, 2), 256, 0, stream>>>(qb, kb, vtb, hid);
    // output projection -> f32
    k_gemm_out<<<dim3(32, 32), 256, 0, stream>>>(hid, wo_t, out);
}

// Round 2
// 939.209 us; speedup vs baseline: 1.1473x; 1.1473x over previous
//
#include <hip/hip_runtime.h>

// ============================================================================
// GLM4-MoE attention layer on MI355X (gfx950), fp16 MFMA pipeline.
// Round 2: flash-attention rewrite — QBLK=128 (32 q-rows/wave), K/V LDS
// double-buffer with counted vmcnt(8), T2 XOR-swizzle on K/V/P tiles
// (pre-swizzled global source + swizzled reads), heavy-first block order.
// GEMMs/aux kernels unchanged from round 1 (known-good).
// ============================================================================

typedef _Float16 f16;
typedef _Float16 f16x8 __attribute__((ext_vector_type(8)));
typedef float f32x4 __attribute__((ext_vector_type(4)));

static constexpr int Bn = 2, Sn = 2048, Hn = 4096, NH = 32, NKV = 8, HD = 128;
static constexpr float SM_SCALE = 0.08838834764831845f; // 1/sqrt(128)

#define AS1 __attribute__((address_space(1)))
#define AS3 __attribute__((address_space(3)))

// async global->LDS, 16B per lane. lds arg must be wave-uniform (HW adds lane*16).
__device__ __forceinline__ void async_ld16(const void* g, void* l) {
    __builtin_amdgcn_global_load_lds((const AS1 void*)g, (AS3 void*)l, 16, 0, 0);
}

// ---------------------------------------------------------------------------
// f32 -> f16 elementwise, 8 elems/thread (n divisible by 8)
__global__ void k_cvt(const float* __restrict__ src, f16* __restrict__ dst, long n) {
    long i = ((long)blockIdx.x * blockDim.x + threadIdx.x) * 8;
    if (i >= n) return;
    float4 a = *(const float4*)(src + i);
    float4 b = *(const float4*)(src + i + 4);
    f16x8 o = {(f16)a.x, (f16)a.y, (f16)a.z, (f16)a.w,
               (f16)b.x, (f16)b.y, (f16)b.z, (f16)b.w};
    *(f16x8*)(dst + i) = o;
}

// ---------------------------------------------------------------------------
// transpose + convert: src f32 [K][N] -> dst f16 [N][K], dst row stride rs elems
__global__ void k_tcvt(const float* __restrict__ src, f16* __restrict__ dst,
                       int K, int N, long rs) {
    __shared__ float tile[32][33];
    int k0 = blockIdx.y * 32, n0 = blockIdx.x * 32;
    int tx = threadIdx.x, ty = threadIdx.y;
#pragma unroll
    for (int r = ty; r < 32; r += 8)
        tile[r][tx] = src[(long)(k0 + r) * N + (n0 + tx)];
    __syncthreads();
#pragma unroll
    for (int r = ty; r < 32; r += 8)
        dst[(long)(n0 + r) * rs + (k0 + tx)] = (f16)tile[tx][r];
}

// ---------------------------------------------------------------------------
// RoPE in-place, interleaved pairs on first 64 dims. x layout [b][nheads][s][128].
__global__ void k_rope(f16* __restrict__ x, const float* __restrict__ cosb,
                       const float* __restrict__ sinb, int nheads) {
    long idx = (long)blockIdx.x * blockDim.x + threadIdx.x;
    int i = (int)(idx & 31);
    long t = idx >> 5;                 // (b*nheads + h)*S + s
    int s = (int)(t & (Sn - 1));
    int bh = (int)(t >> 11);
    int b = bh / nheads;
    long base = t * HD + 2 * i;
    float c = cosb[((long)b * Sn + s) * 64 + i];
    float sv = sinb[((long)b * Sn + s) * 64 + i];
    float x0 = (float)x[base], x1 = (float)x[base + 1];
    x[base]     = (f16)(x0 * c - x1 * sv);
    x[base + 1] = (f16)(x1 * c + x0 * sv);
}

// ---------------------------------------------------------------------------
// V transpose per (b,kv): [S][HD] -> [HD][S]
__global__ void k_tv(const f16* __restrict__ v, f16* __restrict__ vt) {
    __shared__ f16 tile[32][33];
    int bk = blockIdx.z;
    int s0 = blockIdx.x * 32, d0 = blockIdx.y * 32;
    const f16* src = v + (long)bk * Sn * HD;
    f16* dst = vt + (long)bk * Sn * HD;
    int tx = threadIdx.x, ty = threadIdx.y;
#pragma unroll
    for (int r = ty; r < 32; r += 8)
        tile[r][tx] = src[(long)(s0 + r) * HD + (d0 + tx)];
    __syncthreads();
#pragma unroll
    for (int r = ty; r < 32; r += 8)
        dst[(long)(d0 + r) * Sn + (s0 + tx)] = tile[tx][r];
}

// ---------------------------------------------------------------------------
// GEMM core (unchanged, known-good): A f16 [M][4096], Bt f16 [N][4096].
__device__ __forceinline__ void gemm_core(const f16* __restrict__ A,
                                          const f16* __restrict__ Bt,
                                          f16* Asm, f16* Bsm,
                                          int m0, int n0, f32x4 acc[4][4]) {
    const int t = threadIdx.x, lane = t & 63, wave = t >> 6;
    const int wr = wave >> 1, wc = wave & 1;
    const int fr = lane & 15, fg = lane >> 4;
    const int srow = t >> 2;
    const int scol = (t & 3) * 8;
    const f16* ga = A + (long)(m0 + srow) * 4096 + scol;
    const f16* gb = Bt + (long)(n0 + srow) * 4096 + scol;

    for (int k0 = 0; k0 < 4096; k0 += 32) {
        __syncthreads();
        async_ld16(ga + k0,               Asm + wave * 512);
        async_ld16(ga + 64 * 4096 + k0,   Asm + 2048 + wave * 512);
        async_ld16(gb + k0,               Bsm + wave * 512);
        async_ld16(gb + 64 * 4096 + k0,   Bsm + 2048 + wave * 512);
        asm volatile("s_waitcnt vmcnt(0)" ::: "memory");
        __syncthreads();

        f16x8 af[4], bf[4];
#pragma unroll
        for (int mm = 0; mm < 4; ++mm)
            af[mm] = *(const f16x8*)&Asm[(wr * 64 + mm * 16 + fr) * 32 + 8 * fg];
#pragma unroll
        for (int nn = 0; nn < 4; ++nn)
            bf[nn] = *(const f16x8*)&Bsm[(wc * 64 + nn * 16 + fr) * 32 + 8 * fg];
#pragma unroll
        for (int mm = 0; mm < 4; ++mm)
#pragma unroll
            for (int nn = 0; nn < 4; ++nn)
                acc[mm][nn] = __builtin_amdgcn_mfma_f32_16x16x32_f16(
                    af[mm], bf[nn], acc[mm][nn], 0, 0, 0);
    }
}

// GEMM1: hidden[4096][4096] @ Wqkv^T[6144][4096] -> scatter q/k/v f16
__global__ __launch_bounds__(256) void k_gemm_qkv(
    const f16* __restrict__ A, const f16* __restrict__ Bt,
    f16* __restrict__ q, f16* __restrict__ kk_, f16* __restrict__ v) {
    __shared__ __align__(16) f16 Asm[128 * 32];
    __shared__ __align__(16) f16 Bsm[128 * 32];
    int n0 = blockIdx.x * 128, m0 = blockIdx.y * 128;
    f32x4 acc[4][4] = {};
    gemm_core(A, Bt, Asm, Bsm, m0, n0, acc);

    const int lane = threadIdx.x & 63, wave = threadIdx.x >> 6;
    const int wr = wave >> 1, wc = wave & 1;
    const int fr = lane & 15, fg = lane >> 4;
#pragma unroll
    for (int mm = 0; mm < 4; ++mm) {
        int r0 = m0 + wr * 64 + mm * 16 + 4 * fg;
#pragma unroll
        for (int nn = 0; nn < 4; ++nn) {
            int c = n0 + wc * 64 + nn * 16 + fr;
#pragma unroll
            for (int e = 0; e < 4; ++e) {
                int r = r0 + e;
                int b = r >> 11, s = r & (Sn - 1);
                f16 val = (f16)acc[mm][nn][e];
                int d = c & 127;
                if (c < 4096) {
                    int h = c >> 7;
                    q[(((long)b * NH + h) * Sn + s) * HD + d] = val;
                } else if (c < 5120) {
                    int h = (c - 4096) >> 7;
                    kk_[(((long)b * NKV + h) * Sn + s) * HD + d] = val;
                } else {
                    int h = (c - 5120) >> 7;
                    v[(((long)b * NKV + h) * Sn + s) * HD + d] = val;
                }
            }
        }
    }
}

// GEMM2: attn_out[4096][4096] @ wo^T[4096][4096] -> d_out f32
__global__ __launch_bounds__(256) void k_gemm_out(
    const f16* __restrict__ A, const f16* __restrict__ Bt,
    float* __restrict__ out) {
    __shared__ __align__(16) f16 Asm[128 * 32];
    __shared__ __align__(16) f16 Bsm[128 * 32];
    int n0 = blockIdx.x * 128, m0 = blockIdx.y * 128;
    f32x4 acc[4][4] = {};
    gemm_core(A, Bt, Asm, Bsm, m0, n0, acc);

    const int lane = threadIdx.x & 63, wave = threadIdx.x >> 6;
    const int wr = wave >> 1, wc = wave & 1;
    const int fr = lane & 15, fg = lane >> 4;
#pragma unroll
    for (int mm = 0; mm < 4; ++mm) {
        int r0 = m0 + wr * 64 + mm * 16 + 4 * fg;
#pragma unroll
        for (int nn = 0; nn < 4; ++nn) {
            int c = n0 + wc * 64 + nn * 16 + fr;
#pragma unroll
            for (int e = 0; e < 4; ++e)
                out[(long)(r0 + e) * 4096 + c] = acc[mm][nn][e];
        }
    }
}

// ---------------------------------------------------------------------------
// Flash attention v2: causal, GQA. QBLK=128 (4 waves x 32 q-rows), KVBLK=64.
// K/V double-buffered in LDS with counted vmcnt(8); XOR-swizzled tiles.
// Q [b][h][s][d]; K [b][kv][s][d]; Vt [b][kv][d][s]; O [token][NH*HD].
//
// Swizzle scheme (T2): logical (row, colbyte cb) lives at LDS byte
//   row*RB + (cb ^ ((row&7)<<4)),  RB = row bytes (256 for K, 128 for V/P).
// global_load_lds dest stays linear; SOURCE address is inverse-swizzled.

// swizzled fragment read: 8 f16 at logical (r, elem c), row stride 256B
__device__ __forceinline__ f16x8 ld_sw256(const f16* base, int r, int c) {
    int byte = r * 256 + ((c * 2) ^ ((r & 7) << 4));
    return *(const f16x8*)((const char*)base + byte);
}
// row stride 128B
__device__ __forceinline__ f16x8 ld_sw128(const f16* base, int r, int c) {
    int byte = r * 128 + ((c * 2) ^ ((r & 7) << 4));
    return *(const f16x8*)((const char*)base + byte);
}
__device__ __forceinline__ void st_sw128(f16* base, int r, int c, f16 v) {
    int byte = r * 128 + ((c * 2) ^ ((r & 7) << 4));
    *(f16*)((char*)base + byte) = v;
}

// stage K tile [64 kv][128 d] f16 (16KB) into swizzled LDS half
__device__ __forceinline__ void stage_k(const f16* __restrict__ Kb, f16* ksm,
                                        int k0, int wave, int lane) {
#pragma unroll
    for (int i = 0; i < 4; ++i) {
        int dbase = (i * 4 + wave) * 1024;   // wave-uniform dest byte offset
        int d = dbase + lane * 16;           // this lane's dest byte
        int row = d >> 8;
        int cb = (d & 255) ^ ((row & 7) << 4);
        async_ld16(Kb + (long)(k0 + row) * HD + (cb >> 1), (char*)ksm + dbase);
    }
}
// stage V tile [128 d][64 kv] f16 (16KB); Vb is [d][Sn]
__device__ __forceinline__ void stage_v(const f16* __restrict__ Vb, f16* vsm,
                                        int k0, int wave, int lane) {
#pragma unroll
    for (int i = 0; i < 4; ++i) {
        int dbase = (i * 4 + wave) * 1024;
        int d = dbase + lane * 16;
        int row = d >> 7;
        int cb = (d & 127) ^ ((row & 7) << 4);
        async_ld16(Vb + (long)row * Sn + k0 + (cb >> 1), (char*)vsm + dbase);
    }
}

__global__ __launch_bounds__(256) void k_attn(
    const f16* __restrict__ Q, const f16* __restrict__ K,
    const f16* __restrict__ Vt, f16* __restrict__ O) {
    __shared__ __align__(16) f16 Ksm[2][64 * 128];   // 2 x 16KB, swizzled
    __shared__ __align__(16) f16 Vsm[2][128 * 64];   // 2 x 16KB, swizzled
    __shared__ __align__(16) f16 Psm[4][32 * 64];    // per-wave, swizzled (16KB)

    const int qt = (gridDim.x - 1) - blockIdx.x;     // heavy-first
    const int q0 = qt * 128;
    const int h = blockIdx.y, b = blockIdx.z;
    const int kvh = h >> 2;
    const int t = threadIdx.x, lane = t & 63, wave = t >> 6;
    const int q0w = q0 + wave * 32;
    const int fr = lane & 15, fg = lane >> 4;

    const f16* Qb = Q + ((long)(b * NH + h) * Sn) * HD;
    const f16* Kb = K + ((long)(b * NKV + kvh) * Sn) * HD;
    const f16* Vb = Vt + ((long)(b * NKV + kvh) * HD) * Sn;

    // Q fragments: 2 M-frags x 4 k-chunks, resident in regs
    f16x8 qf[2][4];
#pragma unroll
    for (int mq = 0; mq < 2; ++mq)
#pragma unroll
        for (int kk = 0; kk < 4; ++kk)
            qf[mq][kk] = *(const f16x8*)&Qb[(long)(q0w + mq * 16 + fr) * HD + kk * 32 + 8 * fg];

    f32x4 oacc[2][8] = {};
    float mrun[2][4], lrun[2][4];
#pragma unroll
    for (int mq = 0; mq < 2; ++mq)
#pragma unroll
        for (int e = 0; e < 4; ++e) { mrun[mq][e] = -1e30f; lrun[mq][e] = 0.f; }

    const int nt = q0 / 64 + 2;   // tiles up to block diagonal
    // prologue: stage tile 0 into buffer 0
    stage_k(Kb, Ksm[0], 0, wave, lane);
    stage_v(Vb, Vsm[0], 0, wave, lane);

    for (int kt = 0; kt < nt; ++kt) {
        const int k0 = kt * 64;
        const int cur = kt & 1;
        if (kt + 1 < nt) {
            stage_k(Kb, Ksm[cur ^ 1], (kt + 1) * 64, wave, lane);
            stage_v(Vb, Vsm[cur ^ 1], (kt + 1) * 64, wave, lane);
            asm volatile("s_waitcnt vmcnt(8)" ::: "memory"); // drain tile kt only
        } else {
            asm volatile("s_waitcnt vmcnt(0)" ::: "memory");
        }
        __builtin_amdgcn_s_barrier();   // all waves' tile-kt data in LDS

        if (k0 <= q0w + 31) {
            // ---- scores: Q(32x128) . K^T(128x64), 2x4 fragments
            f32x4 sacc[2][4] = {};
#pragma unroll
            for (int nn = 0; nn < 4; ++nn)
#pragma unroll
                for (int kk = 0; kk < 4; ++kk) {
                    f16x8 kf = ld_sw256(Ksm[cur], nn * 16 + fr, kk * 32 + 8 * fg);
#pragma unroll
                    for (int mq = 0; mq < 2; ++mq)
                        sacc[mq][nn] = __builtin_amdgcn_mfma_f32_16x16x32_f16(
                            qf[mq][kk], kf, sacc[mq][nn], 0, 0, 0);
                }
            // ---- mask + scale + row max
            float rmax[2][4];
#pragma unroll
            for (int mq = 0; mq < 2; ++mq)
#pragma unroll
                for (int e = 0; e < 4; ++e) rmax[mq][e] = -1e30f;
#pragma unroll
            for (int mq = 0; mq < 2; ++mq)
#pragma unroll
                for (int nn = 0; nn < 4; ++nn)
#pragma unroll
                    for (int e = 0; e < 4; ++e) {
                        float sv = sacc[mq][nn][e] * SM_SCALE;
                        int skv = k0 + nn * 16 + fr;
                        int sq = q0w + mq * 16 + 4 * fg + e;
                        sv = (skv <= sq) ? sv : -1e30f;
                        sacc[mq][nn][e] = sv;
                        rmax[mq][e] = fmaxf(rmax[mq][e], sv);
                    }
#pragma unroll
            for (int mq = 0; mq < 2; ++mq)
#pragma unroll
                for (int e = 0; e < 4; ++e)
#pragma unroll
                    for (int msk = 1; msk < 16; msk <<= 1)
                        rmax[mq][e] = fmaxf(rmax[mq][e], __shfl_xor(rmax[mq][e], msk, 64));
            // ---- online softmax update (lrun kept as per-lane partial)
            float sc[2][4];
#pragma unroll
            for (int mq = 0; mq < 2; ++mq)
#pragma unroll
                for (int e = 0; e < 4; ++e) {
                    float mn = fmaxf(mrun[mq][e], rmax[mq][e]);
                    sc[mq][e] = __expf(mrun[mq][e] - mn);
                    mrun[mq][e] = mn;
                    lrun[mq][e] *= sc[mq][e];
                }
#pragma unroll
            for (int mq = 0; mq < 2; ++mq)
#pragma unroll
                for (int nn = 0; nn < 4; ++nn)
#pragma unroll
                    for (int e = 0; e < 4; ++e) {
                        float pv = __expf(sacc[mq][nn][e] - mrun[mq][e]);
                        lrun[mq][e] += pv;
                        st_sw128(Psm[wave], mq * 16 + 4 * fg + e, nn * 16 + fr, (f16)pv);
                    }
#pragma unroll
            for (int mq = 0; mq < 2; ++mq)
#pragma unroll
                for (int nd = 0; nd < 8; ++nd)
#pragma unroll
                    for (int e = 0; e < 4; ++e)
                        oacc[mq][nd][e] *= sc[mq][e];
            // P writes -> P reads, same wave; fence + pin schedule
            asm volatile("s_waitcnt lgkmcnt(0)" ::: "memory");
            __builtin_amdgcn_sched_barrier(0);
            // ---- PV: P(32x64) . V^T(64x128)
#pragma unroll
            for (int kk = 0; kk < 2; ++kk) {
                f16x8 pf[2];
#pragma unroll
                for (int mq = 0; mq < 2; ++mq)
                    pf[mq] = ld_sw128(Psm[wave], mq * 16 + fr, kk * 32 + 8 * fg);
#pragma unroll
                for (int nd = 0; nd < 8; ++nd) {
                    f16x8 vf = ld_sw128(Vsm[cur], nd * 16 + fr, kk * 32 + 8 * fg);
#pragma unroll
                    for (int mq = 0; mq < 2; ++mq)
                        oacc[mq][nd] = __builtin_amdgcn_mfma_f32_16x16x32_f16(
                            pf[mq], vf, oacc[mq][nd], 0, 0, 0);
                }
            }
        }
        __builtin_amdgcn_s_barrier();   // all reads of buf done before next overwrite
    }

    // ---- final row-sum reduce (across fr lanes) + normalize + store
#pragma unroll
    for (int mq = 0; mq < 2; ++mq)
#pragma unroll
        for (int e = 0; e < 4; ++e) {
#pragma unroll
            for (int msk = 1; msk < 16; msk <<= 1)
                lrun[mq][e] += __shfl_xor(lrun[mq][e], msk, 64);
        }
    float inv[2][4];
#pragma unroll
    for (int mq = 0; mq < 2; ++mq)
#pragma unroll
        for (int e = 0; e < 4; ++e) inv[mq][e] = 1.f / lrun[mq][e];
#pragma unroll
    for (int mq = 0; mq < 2; ++mq)
#pragma unroll
        for (int nd = 0; nd < 8; ++nd)
#pragma unroll
            for (int e = 0; e < 4; ++e) {
                int srow = q0w + mq * 16 + 4 * fg + e;
                long tok = (long)b * Sn + srow;
                O[tok * (NH * HD) + h * HD + nd * 16 + fr] = (f16)(oacc[mq][nd][e] * inv[mq][e]);
            }
}

// sentinel if workspace too small (distinctive absmax ~1e9)
__global__ void k_ws_fail(float* out) { out[0] = 1.0e9f; }

// ---------------------------------------------------------------------------
extern "C" void kernel_launch(void* const* d_in, const int* in_sizes, int n_in,
                              void* d_out, int out_size, void* d_ws, size_t ws_size,
                              hipStream_t stream) {
    const float* hs   = (const float*)d_in[0];
    const float* wq   = (const float*)d_in[1];
    const float* wk   = (const float*)d_in[2];
    const float* wv   = (const float*)d_in[3];
    const float* wo   = (const float*)d_in[4];
    const float* cosb = (const float*)d_in[5];
    const float* sinb = (const float*)d_in[6];
    float* out = (float*)d_out;

    // workspace layout (bytes)
    const size_t OFF_WQKV = 0;                         // [6144][4096] f16
    const size_t OFF_WO   = 50331648;                  // [4096][4096] f16
    const size_t OFF_HID  = 83886080;                  // [4096][4096] f16 (later attn_out)
    const size_t OFF_Q    = 117440512;                 // [2][32][2048][128] f16
    const size_t OFF_K    = 150994944;                 // [2][8][2048][128] f16
    const size_t OFF_V    = 159383552;                 // [2][8][2048][128] f16
    const size_t OFF_VT   = 167772160;                 // [2][8][128][2048] f16
    const size_t WS_NEED  = 176160768;
    if (ws_size < WS_NEED) { k_ws_fail<<<1, 1, 0, stream>>>(out); return; }

    char* ws = (char*)d_ws;
    f16* wqkv_t = (f16*)(ws + OFF_WQKV);
    f16* wo_t   = (f16*)(ws + OFF_WO);
    f16* hid    = (f16*)(ws + OFF_HID);
    f16* qb     = (f16*)(ws + OFF_Q);
    f16* kb     = (f16*)(ws + OFF_K);
    f16* vb     = (f16*)(ws + OFF_V);
    f16* vtb    = (f16*)(ws + OFF_VT);

    dim3 tb(32, 8);
    k_cvt<<<dim3(16777216 / (256 * 8)), 256, 0, stream>>>(hs, hid, 16777216L);
    k_tcvt<<<dim3(128, 128), tb, 0, stream>>>(wq, wqkv_t, 4096, 4096, 4096);
    k_tcvt<<<dim3(32, 128),  tb, 0, stream>>>(wk, wqkv_t + (long)4096 * 4096, 4096, 1024, 4096);
    k_tcvt<<<dim3(32, 128),  tb, 0, stream>>>(wv, wqkv_t + (long)5120 * 4096, 4096, 1024, 4096);
    k_tcvt<<<dim3(128, 128), tb, 0, stream>>>(wo, wo_t, 4096, 4096, 4096);
    k_gemm_qkv<<<dim3(48, 32), 256, 0, stream>>>(hid, wqkv_t, qb, kb, vb);
    k_rope<<<dim3(2 * 32 * 2048 * 32 / 256), 256, 0, stream>>>(qb, cosb, sinb, NH);
    k_rope<<<dim3(2 * 8 * 2048 * 32 / 256), 256, 0, stream>>>(kb, cosb, sinb, NKV);
    k_tv<<<dim3(64, 4, 16), tb, 0, stream>>>(vb, vtb);
    // flash attention v2: grid (16 qtiles, 32 heads, 2 batch), heavy-first
    k_attn<<<dim3(16, 32, 2), 256, 0, stream>>>(qb, kb, vtb, hid);
    k_gemm_out<<<dim3(32, 32), 256, 0, stream>>>(hid, wo_t, out);
}